// Round 1
// baseline (1094.486 us; speedup 1.0000x reference)
//
#include <hip/hip_runtime.h>
#include <math.h>

#define F   128
#define H   64
#define HH  32

// ---------------------------------------------------------------------------
// Prep: transpose W1 [H][F] -> W1T [F][H], W2 [HH][H] -> W2T [H][HH]
// so the main kernel's inner loops read contiguous weight rows (s_load_x16).
// ---------------------------------------------------------------------------
__global__ void prep_transpose(const float* __restrict__ W1,
                               const float* __restrict__ W2,
                               float* __restrict__ W1T,
                               float* __restrict__ W2T) {
    int t = blockIdx.x * blockDim.x + threadIdx.x;
    if (t < H * F) {                 // 8192
        int j = t / F, f = t % F;    // W1[j][f]
        W1T[f * H + j] = W1[t];
    }
    if (t < HH * H) {                // 2048
        int k = t / H, j = t % H;    // W2[k][j]
        W2T[j * HH + k] = W2[t];
    }
}

__device__ __forceinline__ float gelu_exact(float v) {
    return 0.5f * v * (1.0f + erff(v * 0.70710678118654752440f));
}

// TRANSPOSED=true: W1p=[F][H], W2p=[H][HH]; false: original layouts.
template <bool TRANSPOSED>
__global__ __launch_bounds__(256)
void fused_meta_learner(const float* __restrict__ x,
                        const int*   __restrict__ regime,
                        const float* __restrict__ W1p,
                        const float* __restrict__ b1,
                        const float* __restrict__ gamma,
                        const float* __restrict__ beta,
                        const float* __restrict__ W2p,
                        const float* __restrict__ b2,
                        const float* __restrict__ Wg,   // [2][HH]
                        const float* __restrict__ bg,   // [2]
                        const float* __restrict__ Wr,   // [R][2][HH]
                        const float* __restrict__ br,   // [R][2]
                        const float* __restrict__ emb,  // [R][HH]
                        const float* __restrict__ log_temp,
                        float* __restrict__ out,
                        int B) {
    int row = blockIdx.x * blockDim.x + threadIdx.x;
    if (row >= B) return;

    const float4* __restrict__ x4 =
        reinterpret_cast<const float4*>(x + (size_t)row * F);

    // ---- Layer 1: h = x @ W1.T + b1 --------------------------------------
    float h[H];
#pragma unroll
    for (int j = 0; j < H; ++j) h[j] = b1[j];

    for (int f4 = 0; f4 < F / 4; ++f4) {
        float4 xv = x4[f4];
        if (TRANSPOSED) {
            const float* __restrict__ w0 = W1p + (f4 * 4 + 0) * H;
            const float* __restrict__ w1 = W1p + (f4 * 4 + 1) * H;
            const float* __restrict__ w2 = W1p + (f4 * 4 + 2) * H;
            const float* __restrict__ w3 = W1p + (f4 * 4 + 3) * H;
#pragma unroll
            for (int j = 0; j < H; ++j) {
                float a = h[j];
                a = fmaf(xv.x, w0[j], a);
                a = fmaf(xv.y, w1[j], a);
                a = fmaf(xv.z, w2[j], a);
                a = fmaf(xv.w, w3[j], a);
                h[j] = a;
            }
        } else {
#pragma unroll
            for (int j = 0; j < H; ++j) {
                const float* __restrict__ w = W1p + j * F + f4 * 4;
                float a = h[j];
                a = fmaf(xv.x, w[0], a);
                a = fmaf(xv.y, w[1], a);
                a = fmaf(xv.z, w[2], a);
                a = fmaf(xv.w, w[3], a);
                h[j] = a;
            }
        }
    }

    // ---- LayerNorm + exact GELU ------------------------------------------
    float mu = 0.f;
#pragma unroll
    for (int j = 0; j < H; ++j) mu += h[j];
    mu *= (1.0f / H);
    float var = 0.f;
#pragma unroll
    for (int j = 0; j < H; ++j) {
        float d = h[j] - mu;
        var = fmaf(d, d, var);
    }
    var *= (1.0f / H);
    float rstd = rsqrtf(var + 1e-5f);
#pragma unroll
    for (int j = 0; j < H; ++j) {
        float v = fmaf(gamma[j], (h[j] - mu) * rstd, beta[j]);
        h[j] = gelu_exact(v);
    }

    // ---- Layer 2: h2 = gelu(h @ W2.T + b2) -------------------------------
    float h2[HH];
#pragma unroll
    for (int k = 0; k < HH; ++k) h2[k] = b2[k];

    if (TRANSPOSED) {
#pragma unroll 8
        for (int j = 0; j < H; ++j) {
            float hv = h[j];
            const float* __restrict__ w = W2p + j * HH;
#pragma unroll
            for (int k = 0; k < HH; ++k) h2[k] = fmaf(hv, w[k], h2[k]);
        }
    } else {
#pragma unroll 4
        for (int k = 0; k < HH; ++k) {
            const float* __restrict__ w = W2p + k * H;
            float a = h2[k];
#pragma unroll
            for (int j = 0; j < H; ++j) a = fmaf(h[j], w[j], a);
            h2[k] = a;
        }
    }
#pragma unroll
    for (int k = 0; k < HH; ++k) h2[k] = gelu_exact(h2[k]);

    // ---- Heads -----------------------------------------------------------
    int reg = regime[row];
    const float* __restrict__ wr = Wr + reg * 2 * HH;  // [2][HH] slice
    const float* __restrict__ e  = emb + reg * HH;

    float g0 = bg[0], g1 = bg[1];
    float r0 = br[reg * 2 + 0], r1 = br[reg * 2 + 1];
    float q0 = bg[0], q1 = bg[1];
#pragma unroll
    for (int k = 0; k < HH; ++k) {
        float hv = h2[k];
        float gk = 1.0f / (1.0f + expf(-e[k]));   // sigmoid(emb[reg][k])
        float hg = hv * gk;
        g0 = fmaf(Wg[k],      hv, g0);
        g1 = fmaf(Wg[HH + k], hv, g1);
        r0 = fmaf(wr[k],      hv, r0);
        r1 = fmaf(wr[HH + k], hv, r1);
        q0 = fmaf(Wg[k],      hg, q0);
        q1 = fmaf(Wg[HH + k], hg, q1);
    }

    float temp = expf(log_temp[0]);
    temp = fminf(fmaxf(temp, 0.5f), 5.0f);
    float inv_t = 1.0f / temp;

    float2 res;
    res.x = (0.5f * g0 + 0.3f * r0 + 0.2f * q0) * inv_t;
    res.y = (0.5f * g1 + 0.3f * r1 + 0.2f * q1) * inv_t;
    reinterpret_cast<float2*>(out)[row] = res;
}

extern "C" void kernel_launch(void* const* d_in, const int* in_sizes, int n_in,
                              void* d_out, int out_size, void* d_ws, size_t ws_size,
                              hipStream_t stream) {
    const float* x      = (const float*)d_in[0];
    const int*   regime = (const int*)  d_in[1];
    const float* W1     = (const float*)d_in[2];
    const float* b1     = (const float*)d_in[3];
    const float* gamma  = (const float*)d_in[4];
    const float* beta   = (const float*)d_in[5];
    const float* W2     = (const float*)d_in[6];
    const float* b2     = (const float*)d_in[7];
    const float* Wg     = (const float*)d_in[8];
    const float* bg     = (const float*)d_in[9];
    const float* Wr     = (const float*)d_in[10];
    const float* br     = (const float*)d_in[11];
    const float* emb    = (const float*)d_in[12];
    const float* lt     = (const float*)d_in[13];
    float*       out    = (float*)d_out;

    int B = in_sizes[0] / F;
    int blocks = (B + 255) / 256;

    size_t need = (size_t)(F * H + H * HH) * sizeof(float);
    if (ws_size >= need) {
        float* W1T = (float*)d_ws;       // [F][H]
        float* W2T = W1T + F * H;        // [H][HH]
        prep_transpose<<<dim3((F * H + 255) / 256), dim3(256), 0, stream>>>(
            W1, W2, W1T, W2T);
        fused_meta_learner<true><<<dim3(blocks), dim3(256), 0, stream>>>(
            x, regime, W1T, b1, gamma, beta, W2T, b2, Wg, bg, Wr, br, emb, lt,
            out, B);
    } else {
        fused_meta_learner<false><<<dim3(blocks), dim3(256), 0, stream>>>(
            x, regime, W1, b1, gamma, beta, W2, b2, Wg, bg, Wr, br, emb, lt,
            out, B);
    }
}